// Round 4
// baseline (307.711 us; speedup 1.0000x reference)
//
#include <hip/hip_runtime.h>
#include <math.h>

#define PATTERNS 6
#define ITERS 50
#define LAMBDA_ 100.0f
// 1/(sqrt(2)*SIGMA), SIGMA=1.5
#define CST 0.47140452079103173f

typedef float v2f __attribute__((ext_vector_type(2)));

// all-lanes sum within 8-lane groups (proven __shfl_xor path; DPP banned)
__device__ __forceinline__ float grpsum8(float x) {
    x += __shfl_xor(x, 1, 8);
    x += __shfl_xor(x, 2, 8);
    x += __shfl_xor(x, 4, 8);
    return x;
}

#define PAIRS(X) X(0) X(1) X(2) X(3) X(4) X(5) X(6) X(7) \
                 X(8) X(9) X(10) X(11) X(12) X(13) X(14) X(15)

// 8 lanes per job: lane `sub` owns rows 2*sub, 2*sub+1 (32 px).
// All pixel state in EXPLICIT named registers (no arrays -> no scratch).
__global__ __launch_bounds__(256, 4) void intensity_kernel(
    const float* __restrict__ params,
    const float* __restrict__ data,
    float* __restrict__ out,
    int njobs)
{
    const int tid = blockIdx.x * 256 + threadIdx.x;
    const int job = tid >> 3;
    const int sub = tid & 7;
    if (job >= njobs) return;
    const int spot = job / PATTERNS;

    const float x = params[spot * 5 + 0];
    const float y = params[spot * 5 + 1];
    float I = params[spot * 5 + 4] * (1.0f / PATTERNS);
    float bg = 0.0f;

#define DECLV(k) v2f g##k, s##k;
    PAIRS(DECLV)
#undef DECLV

    // this lane's 32 samples: rows 2*sub, 2*sub+1 contiguous in memory
    {
        const float4* dp = reinterpret_cast<const float4*>(data + (size_t)job * 256 + sub * 32);
        float4 v;
        v = dp[0]; s0  = (v2f){v.x, v.y}; s1  = (v2f){v.z, v.w};
        v = dp[1]; s2  = (v2f){v.x, v.y}; s3  = (v2f){v.z, v.w};
        v = dp[2]; s4  = (v2f){v.x, v.y}; s5  = (v2f){v.z, v.w};
        v = dp[3]; s6  = (v2f){v.x, v.y}; s7  = (v2f){v.z, v.w};
        v = dp[4]; s8  = (v2f){v.x, v.y}; s9  = (v2f){v.z, v.w};
        v = dp[5]; s10 = (v2f){v.x, v.y}; s11 = (v2f){v.z, v.w};
        v = dp[6]; s12 = (v2f){v.x, v.y}; s13 = (v2f){v.z, v.w};
        v = dp[7]; s14 = (v2f){v.x, v.y}; s15 = (v2f){v.z, v.w};
    }

    // psf: g = Ey(row) * Ex(col); rows 2*sub (pairs 0-7), 2*sub+1 (pairs 8-15)
    {
        const float r0f = (float)(2 * sub);
        const float ey_a = erff((r0f - y) * CST);
        const float ey_b = erff((r0f + 1.0f - y) * CST);
        const float ey_c = erff((r0f + 2.0f - y) * CST);
        const float eyl0 = 0.5f * (ey_b - ey_a);
        const float eyl1 = 0.5f * (ey_c - ey_b);
        float e0  = erff((0.0f  - x) * CST);
        float e1  = erff((1.0f  - x) * CST);
        float e2  = erff((2.0f  - x) * CST);
        float e3  = erff((3.0f  - x) * CST);
        float e4  = erff((4.0f  - x) * CST);
        float e5  = erff((5.0f  - x) * CST);
        float e6  = erff((6.0f  - x) * CST);
        float e7  = erff((7.0f  - x) * CST);
        float e8  = erff((8.0f  - x) * CST);
        float e9  = erff((9.0f  - x) * CST);
        float e10 = erff((10.0f - x) * CST);
        float e11 = erff((11.0f - x) * CST);
        float e12 = erff((12.0f - x) * CST);
        float e13 = erff((13.0f - x) * CST);
        float e14 = erff((14.0f - x) * CST);
        float e15 = erff((15.0f - x) * CST);
        float e16 = erff((16.0f - x) * CST);
        v2f ex0 = (v2f){0.5f * (e1  - e0),  0.5f * (e2  - e1)};
        v2f ex1 = (v2f){0.5f * (e3  - e2),  0.5f * (e4  - e3)};
        v2f ex2 = (v2f){0.5f * (e5  - e4),  0.5f * (e6  - e5)};
        v2f ex3 = (v2f){0.5f * (e7  - e6),  0.5f * (e8  - e7)};
        v2f ex4 = (v2f){0.5f * (e9  - e8),  0.5f * (e10 - e9)};
        v2f ex5 = (v2f){0.5f * (e11 - e10), 0.5f * (e12 - e11)};
        v2f ex6 = (v2f){0.5f * (e13 - e12), 0.5f * (e14 - e13)};
        v2f ex7 = (v2f){0.5f * (e15 - e14), 0.5f * (e16 - e15)};
        g0  = eyl0 * ex0; g1  = eyl0 * ex1; g2  = eyl0 * ex2; g3  = eyl0 * ex3;
        g4  = eyl0 * ex4; g5  = eyl0 * ex5; g6  = eyl0 * ex6; g7  = eyl0 * ex7;
        g8  = eyl1 * ex0; g9  = eyl1 * ex1; g10 = eyl1 * ex2; g11 = eyl1 * ex3;
        g12 = eyl1 * ex4; g13 = eyl1 * ex5; g14 = eyl1 * ex6; g15 = eyl1 * ex7;
    }

    // S_psf over all 256 pixels (folded -1 terms of df)
    float spsf;
    {
        v2f sp = (v2f){0.0f, 0.0f};
#define ADDG(k) sp += g##k;
        PAIRS(ADDG)
#undef ADDG
        spsf = grpsum8(sp[0] + sp[1]);
    }

    for (int it = 0; it < ITERS; ++it) {
        const float bge = bg + 1e-9f;   // g>=0 guarantees mu>=1e-9 (matches ref clip regime)
        v2f A0 = (v2f){0.0f, 0.0f}, A1 = (v2f){0.0f, 0.0f}, A2 = (v2f){0.0f, 0.0f};
#define BODY(k) { \
        v2f mu = g##k * I + bge; \
        float rp = __builtin_amdgcn_rcpf(mu[0] * mu[1]); \
        v2f rs = rp * __builtin_shufflevector(mu, mu, 1, 0); \
        v2f u  = s##k * rs * rs; \
        v2f w  = u * g##k; \
        A0 += u; A1 += w; A2 += w * g##k; }
        PAIRS(BODY)
#undef BODY
        float U0 = grpsum8(A0[0] + A0[1]);
        float U1 = grpsum8(A1[0] + A1[1]);
        float U2 = grpsum8(A2[0] + A2[1]);

        // identity t = u*mu: sum(smp/mu) = I*U1 + bg*U0, sum(smp/mu * g) = I*U2 + bg*U1
        float a00 = U2 + LAMBDA_;
        float a01 = U1;
        float a11 = U0 + LAMBDA_;
        float b0 = fmaf(I, U2, bg * U1) - spsf;
        float b1 = fmaf(I, U1, bg * U0) - 256.0f;
        float det = fmaf(a00, a11, -(a01 * a01));
        float rd = __builtin_amdgcn_rcpf(det);
        float dI  = fmaf(a11, b0, -(a01 * b1)) * rd;
        float dbg = fmaf(a00, b1, -(a01 * b0)) * rd;
        I  = fminf(fmaxf(I + dI, 1.0f), 1000000.0f);
        bg = fminf(fmaxf(bg + dbg, 1.0f), 1000.0f);
    }

    // epilogue: CRLB + chisq (once; amortized)
    float F00 = 0.0f, F01 = 0.0f, F11 = 0.0f, chis = 0.0f;
#define EPI(k) { \
        v2f mu = g##k * I + bg; \
        v2f inv; \
        inv[0] = __builtin_amdgcn_rcpf(fmaxf(mu[0], 1e-9f)); \
        inv[1] = __builtin_amdgcn_rcpf(fmaxf(mu[1], 1e-9f)); \
        v2f gi = g##k * inv; \
        v2f d  = s##k - mu; \
        v2f c; \
        c[0] = d[0] * d[0] * __builtin_amdgcn_rcpf(mu[0] + 0.01f); \
        c[1] = d[1] * d[1] * __builtin_amdgcn_rcpf(mu[1] + 0.01f); \
        F00 += gi[0] * g##k[0] + gi[1] * g##k[1]; \
        F01 += gi[0] + gi[1]; \
        F11 += inv[0] + inv[1]; \
        chis += c[0] + c[1]; }
    PAIRS(EPI)
#undef EPI
    F00  = grpsum8(F00);
    F01  = grpsum8(F01);
    F11  = grpsum8(F11);
    chis = grpsum8(chis);

    if (sub == 0) {
        float detF = fmaf(F00, F11, -(F01 * F01));
        float rdF = __builtin_amdgcn_rcpf(detF);
        float* o = out + (size_t)job * 5;
        o[0] = I;
        o[1] = bg;
        o[2] = sqrtf(F11 * rdF);
        o[3] = sqrtf(F00 * rdF);
        o[4] = chis;
    }
}

extern "C" void kernel_launch(void* const* d_in, const int* in_sizes, int n_in,
                              void* d_out, int out_size, void* d_ws, size_t ws_size,
                              hipStream_t stream) {
    const float* params = (const float*)d_in[0];
    const float* data   = (const float*)d_in[1];
    float* out = (float*)d_out;
    int nspots = in_sizes[0] / 5;
    int njobs = nspots * PATTERNS;
    long long nthreads = (long long)njobs * 8;
    int blocks = (int)((nthreads + 255) / 256);
    intensity_kernel<<<dim3(blocks), dim3(256), 0, stream>>>(params, data, out, njobs);
}

// Round 5
// 306.054 us; speedup vs baseline: 1.0054x; 1.0054x over previous
//
#include <hip/hip_runtime.h>
#include <math.h>

#define PATTERNS 6
#define ITERS 50
#define LAMBDA_ 100.0f
// 1/(sqrt(2)*SIGMA), SIGMA=1.5
#define CST 0.47140452079103173f

typedef float v2f __attribute__((ext_vector_type(2)));

// xor-swizzle add within 8-lane groups: new_lane = lane ^ m (BitMode pattern,
// ISA canonical reduction). One DS inst per step, no address VGPR.
__device__ __forceinline__ float grpsum8(float x) {
    x += __int_as_float(__builtin_amdgcn_ds_swizzle(__float_as_int(x), 0x041F)); // xor 1
    x += __int_as_float(__builtin_amdgcn_ds_swizzle(__float_as_int(x), 0x081F)); // xor 2
    x += __int_as_float(__builtin_amdgcn_ds_swizzle(__float_as_int(x), 0x101F)); // xor 4
    return x;
}

#define PAIRS(X) X(0) X(1) X(2) X(3) X(4) X(5) X(6) X(7) \
                 X(8) X(9) X(10) X(11) X(12) X(13) X(14) X(15)

// 8 lanes per job: lane `sub` owns rows 2*sub, 2*sub+1 (32 px, register-resident).
// launch_bounds(256,3): ~168 VGPR cap so pixel state stays in ARCH regs (no AGPR spill copies).
__global__ __launch_bounds__(256, 3) void intensity_kernel(
    const float* __restrict__ params,
    const float* __restrict__ data,
    float* __restrict__ out,
    int njobs)
{
    const int tid = blockIdx.x * 256 + threadIdx.x;
    const int job = tid >> 3;
    const int sub = tid & 7;
    if (job >= njobs) return;
    const int spot = job / PATTERNS;

    const float x = params[spot * 5 + 0];
    const float y = params[spot * 5 + 1];
    float I = params[spot * 5 + 4] * (1.0f / PATTERNS);
    float bg = 0.0f;

#define DECLV(k) v2f g##k, s##k;
    PAIRS(DECLV)
#undef DECLV

    // this lane's 32 samples: rows 2*sub, 2*sub+1 contiguous in memory
    {
        const float4* dp = reinterpret_cast<const float4*>(data + (size_t)job * 256 + sub * 32);
        float4 v;
        v = dp[0]; s0  = (v2f){v.x, v.y}; s1  = (v2f){v.z, v.w};
        v = dp[1]; s2  = (v2f){v.x, v.y}; s3  = (v2f){v.z, v.w};
        v = dp[2]; s4  = (v2f){v.x, v.y}; s5  = (v2f){v.z, v.w};
        v = dp[3]; s6  = (v2f){v.x, v.y}; s7  = (v2f){v.z, v.w};
        v = dp[4]; s8  = (v2f){v.x, v.y}; s9  = (v2f){v.z, v.w};
        v = dp[5]; s10 = (v2f){v.x, v.y}; s11 = (v2f){v.z, v.w};
        v = dp[6]; s12 = (v2f){v.x, v.y}; s13 = (v2f){v.z, v.w};
        v = dp[7]; s14 = (v2f){v.x, v.y}; s15 = (v2f){v.z, v.w};
    }

    // psf: g = Ey(row) * Ex(col); rows 2*sub (pairs 0-7), 2*sub+1 (pairs 8-15)
    {
        const float r0f = (float)(2 * sub);
        const float ey_a = erff((r0f - y) * CST);
        const float ey_b = erff((r0f + 1.0f - y) * CST);
        const float ey_c = erff((r0f + 2.0f - y) * CST);
        const float eyl0 = 0.5f * (ey_b - ey_a);
        const float eyl1 = 0.5f * (ey_c - ey_b);
        float e0  = erff((0.0f  - x) * CST);
        float e1  = erff((1.0f  - x) * CST);
        float e2  = erff((2.0f  - x) * CST);
        float e3  = erff((3.0f  - x) * CST);
        float e4  = erff((4.0f  - x) * CST);
        float e5  = erff((5.0f  - x) * CST);
        float e6  = erff((6.0f  - x) * CST);
        float e7  = erff((7.0f  - x) * CST);
        float e8  = erff((8.0f  - x) * CST);
        float e9  = erff((9.0f  - x) * CST);
        float e10 = erff((10.0f - x) * CST);
        float e11 = erff((11.0f - x) * CST);
        float e12 = erff((12.0f - x) * CST);
        float e13 = erff((13.0f - x) * CST);
        float e14 = erff((14.0f - x) * CST);
        float e15 = erff((15.0f - x) * CST);
        float e16 = erff((16.0f - x) * CST);
        v2f ex0 = (v2f){0.5f * (e1  - e0),  0.5f * (e2  - e1)};
        v2f ex1 = (v2f){0.5f * (e3  - e2),  0.5f * (e4  - e3)};
        v2f ex2 = (v2f){0.5f * (e5  - e4),  0.5f * (e6  - e5)};
        v2f ex3 = (v2f){0.5f * (e7  - e6),  0.5f * (e8  - e7)};
        v2f ex4 = (v2f){0.5f * (e9  - e8),  0.5f * (e10 - e9)};
        v2f ex5 = (v2f){0.5f * (e11 - e10), 0.5f * (e12 - e11)};
        v2f ex6 = (v2f){0.5f * (e13 - e12), 0.5f * (e14 - e13)};
        v2f ex7 = (v2f){0.5f * (e15 - e14), 0.5f * (e16 - e15)};
        g0  = eyl0 * ex0; g1  = eyl0 * ex1; g2  = eyl0 * ex2; g3  = eyl0 * ex3;
        g4  = eyl0 * ex4; g5  = eyl0 * ex5; g6  = eyl0 * ex6; g7  = eyl0 * ex7;
        g8  = eyl1 * ex0; g9  = eyl1 * ex1; g10 = eyl1 * ex2; g11 = eyl1 * ex3;
        g12 = eyl1 * ex4; g13 = eyl1 * ex5; g14 = eyl1 * ex6; g15 = eyl1 * ex7;
    }

    // S_psf over all 256 pixels (folded -1 terms of df)
    float spsf;
    {
        v2f sp = (v2f){0.0f, 0.0f};
#define ADDG(k) sp += g##k;
        PAIRS(ADDG)
#undef ADDG
        spsf = grpsum8(sp[0] + sp[1]);
    }

    for (int it = 0; it < ITERS; ++it) {
        const float bge = bg + 1e-9f;   // g>=0 guarantees mu>=1e-9 (matches ref clip regime)
        v2f A0 = (v2f){0.0f, 0.0f}, A1 = (v2f){0.0f, 0.0f}, A2 = (v2f){0.0f, 0.0f};
#define BODY(k) { \
        v2f mu = g##k * I + bge; \
        float rp = __builtin_amdgcn_rcpf(mu[0] * mu[1]); \
        v2f rs = rp * __builtin_shufflevector(mu, mu, 1, 0); \
        v2f u  = s##k * rs * rs; \
        v2f w  = u * g##k; \
        A0 += u; A1 += w; A2 += w * g##k; }
        PAIRS(BODY)
#undef BODY
        float U0 = grpsum8(A0[0] + A0[1]);
        float U1 = grpsum8(A1[0] + A1[1]);
        float U2 = grpsum8(A2[0] + A2[1]);

        // identity t = u*mu: sum(smp/mu) = I*U1 + bg*U0, sum(smp/mu * g) = I*U2 + bg*U1
        float a00 = U2 + LAMBDA_;
        float a01 = U1;
        float a11 = U0 + LAMBDA_;
        float b0 = fmaf(I, U2, bg * U1) - spsf;
        float b1 = fmaf(I, U1, bg * U0) - 256.0f;
        float det = fmaf(a00, a11, -(a01 * a01));
        float rd = __builtin_amdgcn_rcpf(det);
        float dI  = fmaf(a11, b0, -(a01 * b1)) * rd;
        float dbg = fmaf(a00, b1, -(a01 * b0)) * rd;
        I  = fminf(fmaxf(I + dI, 1.0f), 1000000.0f);
        bg = fminf(fmaxf(bg + dbg, 1.0f), 1000.0f);
    }

    // epilogue: CRLB + chisq (once; amortized)
    float F00 = 0.0f, F01 = 0.0f, F11 = 0.0f, chis = 0.0f;
#define EPI(k) { \
        v2f mu = g##k * I + bg; \
        v2f inv; \
        inv[0] = __builtin_amdgcn_rcpf(fmaxf(mu[0], 1e-9f)); \
        inv[1] = __builtin_amdgcn_rcpf(fmaxf(mu[1], 1e-9f)); \
        v2f gi = g##k * inv; \
        v2f d  = s##k - mu; \
        v2f c; \
        c[0] = d[0] * d[0] * __builtin_amdgcn_rcpf(mu[0] + 0.01f); \
        c[1] = d[1] * d[1] * __builtin_amdgcn_rcpf(mu[1] + 0.01f); \
        F00 += gi[0] * g##k[0] + gi[1] * g##k[1]; \
        F01 += gi[0] + gi[1]; \
        F11 += inv[0] + inv[1]; \
        chis += c[0] + c[1]; }
    PAIRS(EPI)
#undef EPI
    F00  = grpsum8(F00);
    F01  = grpsum8(F01);
    F11  = grpsum8(F11);
    chis = grpsum8(chis);

    if (sub == 0) {
        float detF = fmaf(F00, F11, -(F01 * F01));
        float rdF = __builtin_amdgcn_rcpf(detF);
        float* o = out + (size_t)job * 5;
        o[0] = I;
        o[1] = bg;
        o[2] = sqrtf(F11 * rdF);
        o[3] = sqrtf(F00 * rdF);
        o[4] = chis;
    }
}

extern "C" void kernel_launch(void* const* d_in, const int* in_sizes, int n_in,
                              void* d_out, int out_size, void* d_ws, size_t ws_size,
                              hipStream_t stream) {
    const float* params = (const float*)d_in[0];
    const float* data   = (const float*)d_in[1];
    float* out = (float*)d_out;
    int nspots = in_sizes[0] / 5;
    int njobs = nspots * PATTERNS;
    long long nthreads = (long long)njobs * 8;
    int blocks = (int)((nthreads + 255) / 256);
    intensity_kernel<<<dim3(blocks), dim3(256), 0, stream>>>(params, data, out, njobs);
}

// Round 6
// 278.999 us; speedup vs baseline: 1.1029x; 1.0970x over previous
//
#include <hip/hip_runtime.h>
#include <math.h>

#define PATTERNS 6
#define ITERS 50
#define LAMBDA_ 100.0f
// 1/(sqrt(2)*SIGMA), SIGMA=1.5
#define CST 0.47140452079103173f

typedef float v2f __attribute__((ext_vector_type(2)));

// xor-swizzle add within 8-lane groups (proven; one DS inst per step)
__device__ __forceinline__ float grpsum8(float x) {
    x += __int_as_float(__builtin_amdgcn_ds_swizzle(__float_as_int(x), 0x041F)); // xor 1
    x += __int_as_float(__builtin_amdgcn_ds_swizzle(__float_as_int(x), 0x081F)); // xor 2
    x += __int_as_float(__builtin_amdgcn_ds_swizzle(__float_as_int(x), 0x101F)); // xor 4
    return x;
}

#define PAIRS(X) X(0) X(1) X(2) X(3) X(4) X(5) X(6) X(7) \
                 X(8) X(9) X(10) X(11) X(12) X(13) X(14) X(15)

// 8 lanes per job: lane `sub` owns rows 2*sub, 2*sub+1 (32 px, register-resident).
// 6-op/px inner loop: mu fma, 2 muls for u=s*r*r, A0 add, A1 fma(g), A2 fma(g^2 hoisted).
// rcp per pixel on the trans pipe (overlaps the FMA pipe).
__global__ __launch_bounds__(256, 3) void intensity_kernel(
    const float* __restrict__ params,
    const float* __restrict__ data,
    float* __restrict__ out,
    int njobs)
{
    const int tid = blockIdx.x * 256 + threadIdx.x;
    const int job = tid >> 3;
    const int sub = tid & 7;
    if (job >= njobs) return;
    const int spot = job / PATTERNS;

    const float x = params[spot * 5 + 0];
    const float y = params[spot * 5 + 1];
    float I = params[spot * 5 + 4] * (1.0f / PATTERNS);
    float bg = 0.0f;

#define DECLV(k) v2f g##k, gg##k, s##k;
    PAIRS(DECLV)
#undef DECLV

    // this lane's 32 samples: rows 2*sub, 2*sub+1 contiguous in memory
    {
        const float4* dp = reinterpret_cast<const float4*>(data + (size_t)job * 256 + sub * 32);
        float4 v;
        v = dp[0]; s0  = (v2f){v.x, v.y}; s1  = (v2f){v.z, v.w};
        v = dp[1]; s2  = (v2f){v.x, v.y}; s3  = (v2f){v.z, v.w};
        v = dp[2]; s4  = (v2f){v.x, v.y}; s5  = (v2f){v.z, v.w};
        v = dp[3]; s6  = (v2f){v.x, v.y}; s7  = (v2f){v.z, v.w};
        v = dp[4]; s8  = (v2f){v.x, v.y}; s9  = (v2f){v.z, v.w};
        v = dp[5]; s10 = (v2f){v.x, v.y}; s11 = (v2f){v.z, v.w};
        v = dp[6]; s12 = (v2f){v.x, v.y}; s13 = (v2f){v.z, v.w};
        v = dp[7]; s14 = (v2f){v.x, v.y}; s15 = (v2f){v.z, v.w};
    }

    // psf: g = Ey(row) * Ex(col); rows 2*sub (pairs 0-7), 2*sub+1 (pairs 8-15)
    {
        const float r0f = (float)(2 * sub);
        const float ey_a = erff((r0f - y) * CST);
        const float ey_b = erff((r0f + 1.0f - y) * CST);
        const float ey_c = erff((r0f + 2.0f - y) * CST);
        const float eyl0 = 0.5f * (ey_b - ey_a);
        const float eyl1 = 0.5f * (ey_c - ey_b);
        float e0  = erff((0.0f  - x) * CST);
        float e1  = erff((1.0f  - x) * CST);
        float e2  = erff((2.0f  - x) * CST);
        float e3  = erff((3.0f  - x) * CST);
        float e4  = erff((4.0f  - x) * CST);
        float e5  = erff((5.0f  - x) * CST);
        float e6  = erff((6.0f  - x) * CST);
        float e7  = erff((7.0f  - x) * CST);
        float e8  = erff((8.0f  - x) * CST);
        float e9  = erff((9.0f  - x) * CST);
        float e10 = erff((10.0f - x) * CST);
        float e11 = erff((11.0f - x) * CST);
        float e12 = erff((12.0f - x) * CST);
        float e13 = erff((13.0f - x) * CST);
        float e14 = erff((14.0f - x) * CST);
        float e15 = erff((15.0f - x) * CST);
        float e16 = erff((16.0f - x) * CST);
        v2f ex0 = (v2f){0.5f * (e1  - e0),  0.5f * (e2  - e1)};
        v2f ex1 = (v2f){0.5f * (e3  - e2),  0.5f * (e4  - e3)};
        v2f ex2 = (v2f){0.5f * (e5  - e4),  0.5f * (e6  - e5)};
        v2f ex3 = (v2f){0.5f * (e7  - e6),  0.5f * (e8  - e7)};
        v2f ex4 = (v2f){0.5f * (e9  - e8),  0.5f * (e10 - e9)};
        v2f ex5 = (v2f){0.5f * (e11 - e10), 0.5f * (e12 - e11)};
        v2f ex6 = (v2f){0.5f * (e13 - e12), 0.5f * (e14 - e13)};
        v2f ex7 = (v2f){0.5f * (e15 - e14), 0.5f * (e16 - e15)};
        g0  = eyl0 * ex0; g1  = eyl0 * ex1; g2  = eyl0 * ex2; g3  = eyl0 * ex3;
        g4  = eyl0 * ex4; g5  = eyl0 * ex5; g6  = eyl0 * ex6; g7  = eyl0 * ex7;
        g8  = eyl1 * ex0; g9  = eyl1 * ex1; g10 = eyl1 * ex2; g11 = eyl1 * ex3;
        g12 = eyl1 * ex4; g13 = eyl1 * ex5; g14 = eyl1 * ex6; g15 = eyl1 * ex7;
#define MKGG(k) gg##k = g##k * g##k;
        PAIRS(MKGG)
#undef MKGG
    }

    // S_psf over all 256 pixels (folded -1 terms of df)
    float spsf;
    {
        v2f sp = (v2f){0.0f, 0.0f};
#define ADDG(k) sp += g##k;
        PAIRS(ADDG)
#undef ADDG
        spsf = grpsum8(sp[0] + sp[1]);
    }

    for (int it = 0; it < ITERS; ++it) {
        const float bge = bg + 1e-9f;   // g>=0 guarantees mu>=1e-9 (matches ref clip regime)
        v2f A0 = (v2f){0.0f, 0.0f}, A1 = (v2f){0.0f, 0.0f}, A2 = (v2f){0.0f, 0.0f};
#define BODY(k) { \
        v2f mu = g##k * I + bge; \
        v2f r; \
        r[0] = __builtin_amdgcn_rcpf(mu[0]); \
        r[1] = __builtin_amdgcn_rcpf(mu[1]); \
        v2f u  = (s##k * r) * r; \
        A0 += u; \
        A1 = u * g##k  + A1; \
        A2 = u * gg##k + A2; }
        PAIRS(BODY)
#undef BODY
        float U0 = grpsum8(A0[0] + A0[1]);
        float U1 = grpsum8(A1[0] + A1[1]);
        float U2 = grpsum8(A2[0] + A2[1]);

        // identity t = u*mu: sum(smp/mu) = I*U1 + bg*U0, sum(smp/mu * g) = I*U2 + bg*U1
        float a00 = U2 + LAMBDA_;
        float a01 = U1;
        float a11 = U0 + LAMBDA_;
        float b0 = fmaf(I, U2, bg * U1) - spsf;
        float b1 = fmaf(I, U1, bg * U0) - 256.0f;
        float det = fmaf(a00, a11, -(a01 * a01));
        float rd = __builtin_amdgcn_rcpf(det);
        float dI  = fmaf(a11, b0, -(a01 * b1)) * rd;
        float dbg = fmaf(a00, b1, -(a01 * b0)) * rd;
        I  = fminf(fmaxf(I + dI, 1.0f), 1000000.0f);
        bg = fminf(fmaxf(bg + dbg, 1.0f), 1000.0f);
    }

    // epilogue: CRLB + chisq (once; amortized)
    float F00 = 0.0f, F01 = 0.0f, F11 = 0.0f, chis = 0.0f;
#define EPI(k) { \
        v2f mu = g##k * I + bg; \
        v2f inv; \
        inv[0] = __builtin_amdgcn_rcpf(fmaxf(mu[0], 1e-9f)); \
        inv[1] = __builtin_amdgcn_rcpf(fmaxf(mu[1], 1e-9f)); \
        v2f d  = s##k - mu; \
        v2f c; \
        c[0] = d[0] * d[0] * __builtin_amdgcn_rcpf(mu[0] + 0.01f); \
        c[1] = d[1] * d[1] * __builtin_amdgcn_rcpf(mu[1] + 0.01f); \
        F00 += gg##k[0] * inv[0] + gg##k[1] * inv[1]; \
        F01 += g##k[0]  * inv[0] + g##k[1]  * inv[1]; \
        F11 += inv[0] + inv[1]; \
        chis += c[0] + c[1]; }
    PAIRS(EPI)
#undef EPI
    F00  = grpsum8(F00);
    F01  = grpsum8(F01);
    F11  = grpsum8(F11);
    chis = grpsum8(chis);

    if (sub == 0) {
        float detF = fmaf(F00, F11, -(F01 * F01));
        float rdF = __builtin_amdgcn_rcpf(detF);
        float* o = out + (size_t)job * 5;
        o[0] = I;
        o[1] = bg;
        o[2] = sqrtf(F11 * rdF);
        o[3] = sqrtf(F00 * rdF);
        o[4] = chis;
    }
}

extern "C" void kernel_launch(void* const* d_in, const int* in_sizes, int n_in,
                              void* d_out, int out_size, void* d_ws, size_t ws_size,
                              hipStream_t stream) {
    const float* params = (const float*)d_in[0];
    const float* data   = (const float*)d_in[1];
    float* out = (float*)d_out;
    int nspots = in_sizes[0] / 5;
    int njobs = nspots * PATTERNS;
    long long nthreads = (long long)njobs * 8;
    int blocks = (int)((nthreads + 255) / 256);
    intensity_kernel<<<dim3(blocks), dim3(256), 0, stream>>>(params, data, out, njobs);
}